// Round 1
// baseline (246.241 us; speedup 1.0000x reference)
//
#include <hip/hip_runtime.h>

// 3-level Haar (db1) cascade on [B=4, C=32, 512, 512] fp32.
// Each level: cur4[b, 4c+s, oh, ow], s in {LL,LH,HL,HH}; low = first C
// channels of cur4 (i.e. all 4 subbands of input channels 0..C/4-1),
// high = remaining 3C channels. Output concat: low3, high1, high2, high3, low3.

__global__ __launch_bounds__(256) void haar_step_kernel(
    const float* __restrict__ in,   // [B, C, H, W]
    float* __restrict__ low,        // [B, C, H/2, W/2]
    float* __restrict__ high,       // [B, 3C, H/2, W/2]
    float* __restrict__ low_dup,    // optional second copy of low (may be null)
    int C, int H, int W, int total) // total = B*C*(H/2)*(W/4)
{
    int tid = blockIdx.x * blockDim.x + threadIdx.x;
    if (tid >= total) return;

    const int OH  = H >> 1;
    const int OW  = W >> 1;
    const int OW2 = OW >> 1;   // output column-pairs per row

    int ow2 = tid % OW2;
    int t1  = tid / OW2;
    int oh  = t1 % OH;
    int t2  = t1 / OH;
    int c   = t2 % C;
    int b   = t2 / C;

    const float* rowbase = in + (((size_t)(b * C + c) * H + 2 * oh) * W) + 4 * ow2;
    float4 r0 = *reinterpret_cast<const float4*>(rowbase);       // a0 b0 a1 b1
    float4 r1 = *reinterpret_cast<const float4*>(rowbase + W);   // c0 d0 c1 d1

    float2 ll, lh, hl, hh;
    ll.x = (r0.x + r0.y + r1.x + r1.y) * 0.5f;
    lh.x = (r0.x - r0.y + r1.x - r1.y) * 0.5f;
    hl.x = (r0.x + r0.y - r1.x - r1.y) * 0.5f;
    hh.x = (r0.x - r0.y - r1.x + r1.y) * 0.5f;
    ll.y = (r0.z + r0.w + r1.z + r1.w) * 0.5f;
    lh.y = (r0.z - r0.w + r1.z - r1.w) * 0.5f;
    hl.y = (r0.z + r0.w - r1.z - r1.w) * 0.5f;
    hh.y = (r0.z - r0.w - r1.z + r1.w) * 0.5f;

    const int    baseoc = 4 * c;                 // cur4 channel of LL
    const size_t cs     = (size_t)OH * OW;       // channel plane stride
    const size_t sp     = (size_t)oh * OW + 2 * ow2;

    if (baseoc < C) {
        // all four subband channels land in "low"
        float* p = low + ((size_t)b * C + baseoc) * cs + sp;
        *reinterpret_cast<float2*>(p)          = ll;
        *reinterpret_cast<float2*>(p + cs)     = lh;
        *reinterpret_cast<float2*>(p + 2 * cs) = hl;
        *reinterpret_cast<float2*>(p + 3 * cs) = hh;
        if (low_dup) {
            float* q = low_dup + ((size_t)b * C + baseoc) * cs + sp;
            *reinterpret_cast<float2*>(q)          = ll;
            *reinterpret_cast<float2*>(q + cs)     = lh;
            *reinterpret_cast<float2*>(q + 2 * cs) = hl;
            *reinterpret_cast<float2*>(q + 3 * cs) = hh;
        }
    } else {
        // "high": channels baseoc-C .. baseoc-C+3 of the 3C-channel chunk
        float* p = high + ((size_t)b * (3 * C) + (baseoc - C)) * cs + sp;
        *reinterpret_cast<float2*>(p)          = ll;
        *reinterpret_cast<float2*>(p + cs)     = lh;
        *reinterpret_cast<float2*>(p + 2 * cs) = hl;
        *reinterpret_cast<float2*>(p + 3 * cs) = hh;
    }
}

extern "C" void kernel_launch(void* const* d_in, const int* in_sizes, int n_in,
                              void* d_out, int out_size, void* d_ws, size_t ws_size,
                              hipStream_t stream) {
    const float* x = (const float*)d_in[0];
    float* out = (float*)d_out;

    const int B = 4, C = 32;

    // Output chunk offsets (floats), concat order: low3, high1, high2, high3, low3
    const size_t n_low3  = (size_t)B * C * 64 * 64;        // 524288
    const size_t n_high1 = (size_t)B * 3 * C * 256 * 256;  // 25165824
    const size_t n_high2 = (size_t)B * 3 * C * 128 * 128;  // 6291456
    const size_t n_high3 = (size_t)B * 3 * C * 64 * 64;    // 1572864

    float* low3_a = out;
    float* high1  = out + n_low3;
    float* high2  = high1 + n_high1;
    float* high3  = high2 + n_high2;
    float* low3_b = high3 + n_high3;

    // Workspace: low1 [B,C,256,256] then low2 [B,C,128,128]
    float* ws1 = (float*)d_ws;                    // 8388608 floats
    float* ws2 = ws1 + (size_t)B * C * 256 * 256; // 2097152 floats

    const int threads = 256;

    // Level 1: x [4,32,512,512] -> low1 (ws1), high1 (d_out)
    {
        int total = B * C * 256 * 128;  // 4194304
        int blocks = (total + threads - 1) / threads;
        haar_step_kernel<<<blocks, threads, 0, stream>>>(
            x, ws1, high1, nullptr, C, 512, 512, total);
    }
    // Level 2: low1 [4,32,256,256] -> low2 (ws2), high2 (d_out)
    {
        int total = B * C * 128 * 64;   // 1048576
        int blocks = (total + threads - 1) / threads;
        haar_step_kernel<<<blocks, threads, 0, stream>>>(
            ws1, ws2, high2, nullptr, C, 256, 256, total);
    }
    // Level 3: low2 [4,32,128,128] -> low3 (d_out twice), high3 (d_out)
    {
        int total = B * C * 64 * 32;    // 262144
        int blocks = (total + threads - 1) / threads;
        haar_step_kernel<<<blocks, threads, 0, stream>>>(
            ws2, low3_a, high3, low3_b, C, 128, 128, total);
    }
}

// Round 5
// 235.328 us; speedup vs baseline: 1.0464x; 1.0464x over previous
//
#include <hip/hip_runtime.h>

// Fused 3-level Haar (db1) cascade on [B=4, C=32, 512, 512] fp32.
//
// Channel routing (verified absmax=0 in round 1):
//   L1: cur4 ch = 4c+s.  c>=8 -> high1 ch 4(c-8)+s.  c<8 -> feeds L2.
//   L2: ch2 = 4(4c+s)+s2. c>=2 -> high2 ch 16(c-2)+4s+s2.  c<2 -> feeds L3.
//   L3: ch3 = 64c+4*(4s+s2)+s3. ch3<32 -> low3 (x2), else high3 ch3-32.
//
// No halo: each thread owns an 8x8 input patch -> 4x4 L1 -> 2x2 L2 -> 1x1 L3,
// all in registers. Zero intermediate HBM traffic, one dispatch.

#define HAAR(a, b_, c_, d, o0, o1, o2, o3)       \
    o0 = (a + b_ + c_ + d) * 0.5f;               \
    o1 = (a - b_ + c_ - d) * 0.5f;               \
    o2 = (a + b_ - c_ - d) * 0.5f;               \
    o3 = (a - b_ - c_ + d) * 0.5f;

__global__ __launch_bounds__(256) void haar3_fused(
    const float* __restrict__ x,      // [4,32,512,512]
    float* __restrict__ high1,        // [4,96,256,256]
    float* __restrict__ high2,        // [4,96,128,128]
    float* __restrict__ high3,        // [4,96,64,64]
    float* __restrict__ low3a,        // [4,32,64,64]
    float* __restrict__ low3b)        // duplicate of low3a
{
    const int tid   = threadIdx.x;
    const int tx    = tid & 63;       // column block: cols 8*tx .. 8*tx+7
    const int ty    = tid >> 6;       // row block within tile
    const int tileY = blockIdx.x;     // 16 tiles of 32 rows
    const int bc    = blockIdx.y;     // b*32 + c
    const int c     = bc & 31;
    const int b     = bc >> 5;

    // ---- Level 1: 8x8 patch -> w1[s][i][j] (4 subbands, 4x4 each) ----
    float w1[4][4][4];
    {
        const float* base = x + ((size_t)bc * 512 + (size_t)(tileY * 32 + ty * 8)) * 512
                              + (size_t)tx * 8;
        #pragma unroll
        for (int i = 0; i < 4; ++i) {
            float4 r0a = *(const float4*)(base + (size_t)(2 * i) * 512);
            float4 r0b = *(const float4*)(base + (size_t)(2 * i) * 512 + 4);
            float4 r1a = *(const float4*)(base + (size_t)(2 * i + 1) * 512);
            float4 r1b = *(const float4*)(base + (size_t)(2 * i + 1) * 512 + 4);
            HAAR(r0a.x, r0a.y, r1a.x, r1a.y, w1[0][i][0], w1[1][i][0], w1[2][i][0], w1[3][i][0]);
            HAAR(r0a.z, r0a.w, r1a.z, r1a.w, w1[0][i][1], w1[1][i][1], w1[2][i][1], w1[3][i][1]);
            HAAR(r0b.x, r0b.y, r1b.x, r1b.y, w1[0][i][2], w1[1][i][2], w1[2][i][2], w1[3][i][2]);
            HAAR(r0b.z, r0b.w, r1b.z, r1b.w, w1[0][i][3], w1[1][i][3], w1[2][i][3], w1[3][i][3]);
        }
    }

    if (c >= 8) {
        // All four subbands -> high1, channels 4(c-8)+s. 4x4 block per subband.
        float* hp = high1 + ((size_t)b * 96 + (size_t)(4 * (c - 8))) * (256 * 256)
                          + (size_t)(tileY * 16 + ty * 4) * 256 + (size_t)tx * 4;
        #pragma unroll
        for (int s = 0; s < 4; ++s)
            #pragma unroll
            for (int i = 0; i < 4; ++i)
                *(float4*)(hp + (size_t)s * (256 * 256) + i * 256) =
                    make_float4(w1[s][i][0], w1[s][i][1], w1[s][i][2], w1[s][i][3]);
        return;
    }

    // ---- Level 2: per subband plane, 4x4 -> 2x2 x 4 subbands ----
    float w2[16][2][2];   // [4s+s2][i][j]
    #pragma unroll
    for (int s = 0; s < 4; ++s)
        #pragma unroll
        for (int i = 0; i < 2; ++i)
            #pragma unroll
            for (int j = 0; j < 2; ++j) {
                float a  = w1[s][2 * i][2 * j];
                float bb = w1[s][2 * i][2 * j + 1];
                float cc = w1[s][2 * i + 1][2 * j];
                float dd = w1[s][2 * i + 1][2 * j + 1];
                HAAR(a, bb, cc, dd, w2[4 * s + 0][i][j], w2[4 * s + 1][i][j],
                                    w2[4 * s + 2][i][j], w2[4 * s + 3][i][j]);
            }

    if (c >= 2) {
        // 16 planes -> high2, channels 16(c-2) + j2. 2x2 block per plane.
        float* hp = high2 + ((size_t)b * 96 + (size_t)(16 * (c - 2))) * (128 * 128)
                          + (size_t)(tileY * 8 + ty * 2) * 128 + (size_t)tx * 2;
        #pragma unroll
        for (int j2 = 0; j2 < 16; ++j2)
            #pragma unroll
            for (int i = 0; i < 2; ++i)
                *(float2*)(hp + (size_t)j2 * (128 * 128) + i * 128) =
                    make_float2(w2[j2][i][0], w2[j2][i][1]);
        return;
    }

    // ---- Level 3 (c in {0,1}): per plane 2x2 -> 4 scalars, routed ----
    const size_t p3  = 64 * 64;
    const size_t sp3 = (size_t)(tileY * 4 + ty) * 64 + (size_t)tx;
    #pragma unroll
    for (int j2 = 0; j2 < 16; ++j2) {
        float a  = w2[j2][0][0];
        float bb = w2[j2][0][1];
        float cc = w2[j2][1][0];
        float dd = w2[j2][1][1];
        float v0, v1, v2, v3;
        HAAR(a, bb, cc, dd, v0, v1, v2, v3);
        float v[4] = {v0, v1, v2, v3};
        #pragma unroll
        for (int s3 = 0; s3 < 4; ++s3) {
            int ch = 64 * c + 4 * j2 + s3;
            if (ch < 32) {
                low3a[((size_t)b * 32 + ch) * p3 + sp3] = v[s3];
                low3b[((size_t)b * 32 + ch) * p3 + sp3] = v[s3];
            } else {
                high3[((size_t)b * 96 + (ch - 32)) * p3 + sp3] = v[s3];
            }
        }
    }
}

extern "C" void kernel_launch(void* const* d_in, const int* in_sizes, int n_in,
                              void* d_out, int out_size, void* d_ws, size_t ws_size,
                              hipStream_t stream) {
    const float* x = (const float*)d_in[0];
    float* out = (float*)d_out;

    const size_t n_low3  = (size_t)4 * 32 * 64 * 64;
    const size_t n_high1 = (size_t)4 * 96 * 256 * 256;
    const size_t n_high2 = (size_t)4 * 96 * 128 * 128;
    const size_t n_high3 = (size_t)4 * 96 * 64 * 64;

    float* low3a = out;
    float* high1 = out + n_low3;
    float* high2 = high1 + n_high1;
    float* high3 = high2 + n_high2;
    float* low3b = high3 + n_high3;

    dim3 grid(16, 128);   // 16 row-tiles x (b*32+c)
    haar3_fused<<<grid, 256, 0, stream>>>(x, high1, high2, high3, low3a, low3b);
}

// Round 7
// 233.958 us; speedup vs baseline: 1.0525x; 1.0059x over previous
//
#include <hip/hip_runtime.h>

// Fused 3-level Haar (db1) cascade on [B=4, C=32, 512, 512] fp32.
//
// Channel routing (verified absmax=0):
//   L1: cur4 ch = 4c+s.  c>=8 -> high1 ch 4(c-8)+s.  c<8 -> feeds L2.
//   L2: ch2 = 4(4c+s)+s2. c>=2 -> high2 ch 16(c-2)+4s+s2.  c<2 -> feeds L3.
//   L3: ch3 = 64c+4*(4s+s2)+s3. ch3<32 -> low3 (x2), else high3 ch3-32.
//
// Round-5 counters: 84.5us @ 2.45 TB/s, VALUBusy 4%, FETCH 69MB (x half
// L3-resident), WRITE 136MB. Theory: output write-allocation churns L3
// (harness poisons 545MB + restores x right before us). Fix: non-temporal
// stores for ALL outputs (no L3 allocation; x stays resident).

typedef float f4 __attribute__((ext_vector_type(4)));
typedef float f2 __attribute__((ext_vector_type(2)));

#define HAAR(a, b_, c_, d, o0, o1, o2, o3)       \
    o0 = (a + b_ + c_ + d) * 0.5f;               \
    o1 = (a - b_ + c_ - d) * 0.5f;               \
    o2 = (a + b_ - c_ - d) * 0.5f;               \
    o3 = (a - b_ - c_ + d) * 0.5f;

__global__ __launch_bounds__(256) void haar3_fused(
    const float* __restrict__ x,      // [4,32,512,512]
    float* __restrict__ high1,        // [4,96,256,256]
    float* __restrict__ high2,        // [4,96,128,128]
    float* __restrict__ high3,        // [4,96,64,64]
    float* __restrict__ low3a,        // [4,32,64,64]
    float* __restrict__ low3b)        // duplicate of low3a
{
    const int tid   = threadIdx.x;
    const int tx    = tid & 63;       // column block: cols 8*tx .. 8*tx+7
    const int ty    = tid >> 6;       // row block within tile
    const int tileY = blockIdx.x;     // 16 tiles of 32 rows
    const int bc    = blockIdx.y;     // b*32 + c
    const int c     = bc & 31;
    const int b     = bc >> 5;

    // ---- Level 1: 8x8 patch -> w1[s][i][j] (4 subbands, 4x4 each) ----
    float w1[4][4][4];
    {
        const float* base = x + ((size_t)bc * 512 + (size_t)(tileY * 32 + ty * 8)) * 512
                              + (size_t)tx * 8;
        #pragma unroll
        for (int i = 0; i < 4; ++i) {
            f4 r0a = *(const f4*)(base + (size_t)(2 * i) * 512);
            f4 r0b = *(const f4*)(base + (size_t)(2 * i) * 512 + 4);
            f4 r1a = *(const f4*)(base + (size_t)(2 * i + 1) * 512);
            f4 r1b = *(const f4*)(base + (size_t)(2 * i + 1) * 512 + 4);
            HAAR(r0a.x, r0a.y, r1a.x, r1a.y, w1[0][i][0], w1[1][i][0], w1[2][i][0], w1[3][i][0]);
            HAAR(r0a.z, r0a.w, r1a.z, r1a.w, w1[0][i][1], w1[1][i][1], w1[2][i][1], w1[3][i][1]);
            HAAR(r0b.x, r0b.y, r1b.x, r1b.y, w1[0][i][2], w1[1][i][2], w1[2][i][2], w1[3][i][2]);
            HAAR(r0b.z, r0b.w, r1b.z, r1b.w, w1[0][i][3], w1[1][i][3], w1[2][i][3], w1[3][i][3]);
        }
    }

    if (c >= 8) {
        // All four subbands -> high1, channels 4(c-8)+s. 4x4 block per subband.
        float* hp = high1 + ((size_t)b * 96 + (size_t)(4 * (c - 8))) * (256 * 256)
                          + (size_t)(tileY * 16 + ty * 4) * 256 + (size_t)tx * 4;
        #pragma unroll
        for (int s = 0; s < 4; ++s)
            #pragma unroll
            for (int i = 0; i < 4; ++i) {
                f4 v = {w1[s][i][0], w1[s][i][1], w1[s][i][2], w1[s][i][3]};
                __builtin_nontemporal_store(v, (f4*)(hp + (size_t)s * (256 * 256) + i * 256));
            }
        return;
    }

    // ---- Level 2: per subband plane, 4x4 -> 2x2 x 4 subbands ----
    float w2[16][2][2];   // [4s+s2][i][j]
    #pragma unroll
    for (int s = 0; s < 4; ++s)
        #pragma unroll
        for (int i = 0; i < 2; ++i)
            #pragma unroll
            for (int j = 0; j < 2; ++j) {
                float a  = w1[s][2 * i][2 * j];
                float bb = w1[s][2 * i][2 * j + 1];
                float cc = w1[s][2 * i + 1][2 * j];
                float dd = w1[s][2 * i + 1][2 * j + 1];
                HAAR(a, bb, cc, dd, w2[4 * s + 0][i][j], w2[4 * s + 1][i][j],
                                    w2[4 * s + 2][i][j], w2[4 * s + 3][i][j]);
            }

    if (c >= 2) {
        // 16 planes -> high2, channels 16(c-2) + j2. 2x2 block per plane.
        float* hp = high2 + ((size_t)b * 96 + (size_t)(16 * (c - 2))) * (128 * 128)
                          + (size_t)(tileY * 8 + ty * 2) * 128 + (size_t)tx * 2;
        #pragma unroll
        for (int j2 = 0; j2 < 16; ++j2)
            #pragma unroll
            for (int i = 0; i < 2; ++i) {
                f2 v = {w2[j2][i][0], w2[j2][i][1]};
                __builtin_nontemporal_store(v, (f2*)(hp + (size_t)j2 * (128 * 128) + i * 128));
            }
        return;
    }

    // ---- Level 3 (c in {0,1}): per plane 2x2 -> 4 scalars, routed ----
    const size_t p3  = 64 * 64;
    const size_t sp3 = (size_t)(tileY * 4 + ty) * 64 + (size_t)tx;
    #pragma unroll
    for (int j2 = 0; j2 < 16; ++j2) {
        float a  = w2[j2][0][0];
        float bb = w2[j2][0][1];
        float cc = w2[j2][1][0];
        float dd = w2[j2][1][1];
        float v0, v1, v2, v3;
        HAAR(a, bb, cc, dd, v0, v1, v2, v3);
        float v[4] = {v0, v1, v2, v3};
        #pragma unroll
        for (int s3 = 0; s3 < 4; ++s3) {
            int ch = 64 * c + 4 * j2 + s3;
            if (ch < 32) {
                __builtin_nontemporal_store(v[s3], low3a + ((size_t)b * 32 + ch) * p3 + sp3);
                __builtin_nontemporal_store(v[s3], low3b + ((size_t)b * 32 + ch) * p3 + sp3);
            } else {
                __builtin_nontemporal_store(v[s3], high3 + ((size_t)b * 96 + (ch - 32)) * p3 + sp3);
            }
        }
    }
}

extern "C" void kernel_launch(void* const* d_in, const int* in_sizes, int n_in,
                              void* d_out, int out_size, void* d_ws, size_t ws_size,
                              hipStream_t stream) {
    const float* x = (const float*)d_in[0];
    float* out = (float*)d_out;

    const size_t n_low3  = (size_t)4 * 32 * 64 * 64;
    const size_t n_high1 = (size_t)4 * 96 * 256 * 256;
    const size_t n_high2 = (size_t)4 * 96 * 128 * 128;
    const size_t n_high3 = (size_t)4 * 96 * 64 * 64;

    float* low3a = out;
    float* high1 = out + n_low3;
    float* high2 = high1 + n_high1;
    float* high3 = high2 + n_high2;
    float* low3b = high3 + n_high3;

    dim3 grid(16, 128);   // 16 row-tiles x (b*32+c)
    haar3_fused<<<grid, 256, 0, stream>>>(x, high1, high2, high3, low3a, low3b);
}

// Round 9
// 231.604 us; speedup vs baseline: 1.0632x; 1.0102x over previous
//
#include <hip/hip_runtime.h>

// 3-level Haar cascade, split by channel role.
//  K1: c in [8,32) -> high1 only (75% of traffic). Dense 16B/lane loads
//      (round-1 pattern, measured ~4.5+ TB/s aggregate), f2 stores.
//  K2: c in [0,8)  -> fused L1+L2+L3 in registers (8x8 patch per thread).
// Routing (verified absmax=0 rounds 1/5/7):
//   L1: ch=4c+s; c>=8 -> high1 ch 4(c-8)+s.
//   L2: c>=2 -> high2 ch 16(c-2)+4s+s2.
//   L3: ch3=64c+16s+4s2+s3; ch3<32 -> low3 (x2) else high3 ch3-32.

typedef float f4 __attribute__((ext_vector_type(4)));
typedef float f2 __attribute__((ext_vector_type(2)));

#define HAAR(a, b_, c_, d, o0, o1, o2, o3)       \
    o0 = (a + b_ + c_ + d) * 0.5f;               \
    o1 = (a - b_ + c_ - d) * 0.5f;               \
    o2 = (a + b_ - c_ - d) * 0.5f;               \
    o3 = (a - b_ - c_ + d) * 0.5f;

// ---------------- K1: level-1-only channels (c = 8..31) ----------------
__global__ __launch_bounds__(256) void haar_l1_high(
    const float* __restrict__ x,      // [4,32,512,512]
    float* __restrict__ high1)        // [4,96,256,256]
{
    const int tid = threadIdx.x;
    const int ow2 = tid & 127;                        // output col pair 0..127
    const int oh  = (blockIdx.x << 1) | (tid >> 7);   // output row 0..255
    const int bc  = blockIdx.y;                       // b*24 + (c-8)
    const int c24 = bc % 24;
    const int b   = bc / 24;

    const float* rowbase = x + ((size_t)(b * 32 + c24 + 8) * 512 + (size_t)(2 * oh)) * 512
                             + (size_t)(4 * ow2);
    f4 r0 = *(const f4*)(rowbase);          // a0 b0 a1 b1   (dense: 16B * lane)
    f4 r1 = *(const f4*)(rowbase + 512);    // c0 d0 c1 d1

    f2 ll, lh, hl, hh;
    HAAR(r0.x, r0.y, r1.x, r1.y, ll.x, lh.x, hl.x, hh.x);
    HAAR(r0.z, r0.w, r1.z, r1.w, ll.y, lh.y, hl.y, hh.y);

    float* hp = high1 + ((size_t)b * 96 + (size_t)(4 * c24)) * (256 * 256)
                      + (size_t)oh * 256 + (size_t)(2 * ow2);
    __builtin_nontemporal_store(ll, (f2*)(hp));
    __builtin_nontemporal_store(lh, (f2*)(hp + 1 * 256 * 256));
    __builtin_nontemporal_store(hl, (f2*)(hp + 2 * 256 * 256));
    __builtin_nontemporal_store(hh, (f2*)(hp + 3 * 256 * 256));
}

// ---------------- K2: recursive channels (c = 0..7), fused 3 levels ----------------
__global__ __launch_bounds__(256) void haar3_low(
    const float* __restrict__ x,      // [4,32,512,512]
    float* __restrict__ high2,        // [4,96,128,128]
    float* __restrict__ high3,        // [4,96,64,64]
    float* __restrict__ low3a,        // [4,32,64,64]
    float* __restrict__ low3b)
{
    const int tid   = threadIdx.x;
    const int tx    = tid & 63;       // column block: cols 8*tx .. 8*tx+7
    const int ty    = tid >> 6;       // row block within tile
    const int tileY = blockIdx.x;     // 16 tiles of 32 rows
    const int bc    = blockIdx.y;     // b*8 + c
    const int c     = bc & 7;
    const int b     = bc >> 3;

    // Level 1: 8x8 patch -> w1[s][i][j]
    float w1[4][4][4];
    {
        const float* base = x + ((size_t)(b * 32 + c) * 512 + (size_t)(tileY * 32 + ty * 8)) * 512
                              + (size_t)tx * 8;
        #pragma unroll
        for (int i = 0; i < 4; ++i) {
            f4 r0a = *(const f4*)(base + (size_t)(2 * i) * 512);
            f4 r0b = *(const f4*)(base + (size_t)(2 * i) * 512 + 4);
            f4 r1a = *(const f4*)(base + (size_t)(2 * i + 1) * 512);
            f4 r1b = *(const f4*)(base + (size_t)(2 * i + 1) * 512 + 4);
            HAAR(r0a.x, r0a.y, r1a.x, r1a.y, w1[0][i][0], w1[1][i][0], w1[2][i][0], w1[3][i][0]);
            HAAR(r0a.z, r0a.w, r1a.z, r1a.w, w1[0][i][1], w1[1][i][1], w1[2][i][1], w1[3][i][1]);
            HAAR(r0b.x, r0b.y, r1b.x, r1b.y, w1[0][i][2], w1[1][i][2], w1[2][i][2], w1[3][i][2]);
            HAAR(r0b.z, r0b.w, r1b.z, r1b.w, w1[0][i][3], w1[1][i][3], w1[2][i][3], w1[3][i][3]);
        }
    }

    // Level 2: per subband plane, 4x4 -> 2x2 x 4
    float w2[16][2][2];
    #pragma unroll
    for (int s = 0; s < 4; ++s)
        #pragma unroll
        for (int i = 0; i < 2; ++i)
            #pragma unroll
            for (int j = 0; j < 2; ++j) {
                float a  = w1[s][2 * i][2 * j];
                float bb = w1[s][2 * i][2 * j + 1];
                float cc = w1[s][2 * i + 1][2 * j];
                float dd = w1[s][2 * i + 1][2 * j + 1];
                HAAR(a, bb, cc, dd, w2[4 * s + 0][i][j], w2[4 * s + 1][i][j],
                                    w2[4 * s + 2][i][j], w2[4 * s + 3][i][j]);
            }

    if (c >= 2) {
        float* hp = high2 + ((size_t)b * 96 + (size_t)(16 * (c - 2))) * (128 * 128)
                          + (size_t)(tileY * 8 + ty * 2) * 128 + (size_t)tx * 2;
        #pragma unroll
        for (int j2 = 0; j2 < 16; ++j2)
            #pragma unroll
            for (int i = 0; i < 2; ++i) {
                f2 v = {w2[j2][i][0], w2[j2][i][1]};
                __builtin_nontemporal_store(v, (f2*)(hp + (size_t)j2 * (128 * 128) + i * 128));
            }
        return;
    }

    // Level 3 (c in {0,1})
    const size_t p3  = 64 * 64;
    const size_t sp3 = (size_t)(tileY * 4 + ty) * 64 + (size_t)tx;
    #pragma unroll
    for (int j2 = 0; j2 < 16; ++j2) {
        float a  = w2[j2][0][0];
        float bb = w2[j2][0][1];
        float cc = w2[j2][1][0];
        float dd = w2[j2][1][1];
        float v0, v1, v2, v3;
        HAAR(a, bb, cc, dd, v0, v1, v2, v3);
        float v[4] = {v0, v1, v2, v3};
        #pragma unroll
        for (int s3 = 0; s3 < 4; ++s3) {
            int ch = 64 * c + 4 * j2 + s3;
            if (ch < 32) {
                __builtin_nontemporal_store(v[s3], low3a + ((size_t)b * 32 + ch) * p3 + sp3);
                __builtin_nontemporal_store(v[s3], low3b + ((size_t)b * 32 + ch) * p3 + sp3);
            } else {
                __builtin_nontemporal_store(v[s3], high3 + ((size_t)b * 96 + (ch - 32)) * p3 + sp3);
            }
        }
    }
}

extern "C" void kernel_launch(void* const* d_in, const int* in_sizes, int n_in,
                              void* d_out, int out_size, void* d_ws, size_t ws_size,
                              hipStream_t stream) {
    const float* x = (const float*)d_in[0];
    float* out = (float*)d_out;

    const size_t n_low3  = (size_t)4 * 32 * 64 * 64;
    const size_t n_high1 = (size_t)4 * 96 * 256 * 256;
    const size_t n_high2 = (size_t)4 * 96 * 128 * 128;
    const size_t n_high3 = (size_t)4 * 96 * 64 * 64;

    float* low3a = out;
    float* high1 = out + n_low3;
    float* high2 = high1 + n_high1;
    float* high3 = high2 + n_high2;
    float* low3b = high3 + n_high3;

    // K1: c in [8,32). grid: x = 128 (2 output rows/block), y = b*24+(c-8)
    haar_l1_high<<<dim3(128, 96), 256, 0, stream>>>(x, high1);
    // K2: c in [0,8). grid: x = 16 row-tiles, y = b*8+c
    haar3_low<<<dim3(16, 32), 256, 0, stream>>>(x, high2, high3, low3a, low3b);
}